// Round 8
// baseline (2304.169 us; speedup 1.0000x reference)
//
#include <hip/hip_runtime.h>

typedef unsigned short ushortT;
typedef short bf16x8 __attribute__((ext_vector_type(8)));   // 8 bf16 in 4 VGPRs
typedef float f32x4 __attribute__((ext_vector_type(4)));

#define NDIM 2048
#define NTOT (2048 * 2048)
#define N4 (NTOT / 4)
#define N16 (NTOT / 8)     // threads at 8 bf16 (16B) per thread
#define BK 64
#define GEMM_BLOCKS 1024   // 64x64 tiles on 32x32 grid, XCD-supertiled

__device__ __forceinline__ ushortT f2bf(float f) {
    unsigned u = __float_as_uint(f);
    u += 0x7fffu + ((u >> 16) & 1u);   // RNE; inputs finite
    return (ushortT)(u >> 16);
}
__device__ __forceinline__ float bf2f(ushortT u) {
    return __uint_as_float((unsigned)u << 16);
}
__device__ __forceinline__ float tanh_fast(float x) {
    float e = __expf(2.0f * x);
    return 1.0f - 2.0f / (e + 1.0f);
}
__device__ __forceinline__ void gload_lds16(const void* g, void* l) {
    __builtin_amdgcn_global_load_lds(
        (const __attribute__((address_space(1))) void*)g,
        (__attribute__((address_space(3))) void*)l, 16, 0, 0);
}
__device__ __forceinline__ unsigned hash_u32(unsigned x) {
    x ^= x >> 16; x *= 0x7feb352du; x ^= x >> 15; x *= 0x846ca68bu; x ^= x >> 16;
    return x;
}
// unpack 8 bf16 (uint4) -> 8 f32; element order consistent across all users
__device__ __forceinline__ void unpack8(uint4 v, float* f) {
    f[0] = __uint_as_float(v.x << 16); f[1] = __uint_as_float(v.x & 0xffff0000u);
    f[2] = __uint_as_float(v.y << 16); f[3] = __uint_as_float(v.y & 0xffff0000u);
    f[4] = __uint_as_float(v.z << 16); f[5] = __uint_as_float(v.z & 0xffff0000u);
    f[6] = __uint_as_float(v.w << 16); f[7] = __uint_as_float(v.w & 0xffff0000u);
}
__device__ __forceinline__ uint4 pack8(const float* f) {
    uint4 v;
    v.x = (unsigned)f2bf(f[0]) | ((unsigned)f2bf(f[1]) << 16);
    v.y = (unsigned)f2bf(f[2]) | ((unsigned)f2bf(f[3]) << 16);
    v.z = (unsigned)f2bf(f[4]) | ((unsigned)f2bf(f[5]) << 16);
    v.w = (unsigned)f2bf(f[6]) | ((unsigned)f2bf(f[7]) << 16);
    return v;
}

// 5x5 ridge-normal-equation solve (LU w/ pivoting, fp64), alpha normalized.
__device__ void solve5(const float* dots, float* alphaOut, int nk) {
    double H[5][5], rhs[5], x[5];
    for (int i = 0; i < nk; ++i) {
        for (int j = 0; j < nk; ++j)
            H[i][j] = (double)dots[i * 5 + j] + (i == j ? 1e-4 : 0.0);
        rhs[i] = 1.0;
    }
    for (int c = 0; c < nk; ++c) {
        int p = c; double mx = fabs(H[c][c]);
        for (int r = c + 1; r < nk; ++r) { double a = fabs(H[r][c]); if (a > mx) { mx = a; p = r; } }
        if (p != c) {
            for (int j = 0; j < nk; ++j) { double tv = H[c][j]; H[c][j] = H[p][j]; H[p][j] = tv; }
            double tr = rhs[c]; rhs[c] = rhs[p]; rhs[p] = tr;
        }
        double d = H[c][c]; if (fabs(d) < 1e-300) d = 1e-300;
        for (int r = c + 1; r < nk; ++r) {
            double f = H[r][c] / d;
            for (int j = c; j < nk; ++j) H[r][j] -= f * H[c][j];
            rhs[r] -= f * rhs[c];
        }
    }
    for (int c = nk - 1; c >= 0; --c) {
        double v = rhs[c];
        for (int j = c + 1; j < nk; ++j) v -= H[c][j] * x[j];
        double d = H[c][c]; if (fabs(d) < 1e-300) d = 1e-300;
        x[c] = v / d;
    }
    double sum = 0.0;
    for (int i = 0; i < nk; ++i) sum += x[i];
    if (sum == 0.0) sum = 1.0;
    for (int i = 0; i < 5; ++i) alphaOut[i] = (i < nk) ? (float)(x[i] / sum) : 0.f;
}

// ---------------- transpose + cast: W (f32 [k][n]) -> WT bf16 [n][k]
__global__ void k_transpose(const float* __restrict__ W, ushortT* __restrict__ WT) {
    __shared__ float tile[32][33];
    const int bx = blockIdx.x * 32, by = blockIdx.y * 32;
    const int tx = threadIdx.x, ty = threadIdx.y;  // (32,8)
#pragma unroll
    for (int r = 0; r < 32; r += 8)
        tile[ty + r][tx] = W[(size_t)(by + ty + r) * NDIM + bx + tx];
    __syncthreads();
#pragma unroll
    for (int r = 0; r < 32; r += 8)
        WT[(size_t)(bx + ty + r) * NDIM + by + tx] = f2bf(tile[tx][ty + r]);
}

// ---------------- init: F0(bf16) = G0(bf16) = Abf = bf16(tanh(u));
//                  dots[0][0] += <g0,g0>  (dots pre-zeroed by memset)
__global__ void k_init(const float* __restrict__ U, ushortT* __restrict__ F0,
                       ushortT* __restrict__ G0, ushortT* __restrict__ Abf,
                       float* __restrict__ dots) {
    const int stride = gridDim.x * blockDim.x;
    float psum = 0.f;
    for (int i = blockIdx.x * blockDim.x + threadIdx.x; i < N4; i += stride) {
        float4 u = ((const float4*)U)[i];
        float4 t;
        t.x = tanh_fast(u.x); t.y = tanh_fast(u.y);
        t.z = tanh_fast(u.z); t.w = tanh_fast(u.w);
        ushort4 p; p.x = f2bf(t.x); p.y = f2bf(t.y); p.z = f2bf(t.z); p.w = f2bf(t.w);
        ((ushort4*)F0)[i] = p;
        ((ushort4*)G0)[i] = p;
        ((ushort4*)Abf)[i] = p;
        // dot of the STORED (bf16-rounded) residual, consistent with k_dotsG
        float a = bf2f(p.x), b = bf2f(p.y), c = bf2f(p.z), d = bf2f(p.w);
        psum += a * a + b * b + c * c + d * d;
    }
#pragma unroll
    for (int off = 32; off > 0; off >>= 1) psum += __shfl_down(psum, off);
    __shared__ float red[4];
    const int w = threadIdx.x >> 6, lane = threadIdx.x & 63;
    if (lane == 0) red[w] = psum;
    __syncthreads();
    if (threadIdx.x == 0)
        atomicAdd(dots, red[0] + red[1] + red[2] + red[3]);
}

// ---------------- GEMM: C = A(bf16)[64 rows] @ Bt(bf16)[64 rows]^T, BK=64, swizzled LDS
// MODE 0: (float*)FoutV = tanh(C + U)                      [f32 final output]
// MODE 1: jac += sum(((1-xstar^2)*C)^2)/NTOT               (A = eps)
// MODE 2: f = tanh(C+U); (ushort*)FoutV = bf16(f); G[s] = bf16(f - bf2f(Xbf))
//         (Xbf = Abf = bf16(xk); bf16 rounding of xk is at the noise level of f itself)
// Grid: 1D, XCD-supertiled (chunk=id&7 owns 8x16 contiguous supertile).
// LDS swizzle (both-sides, rule #21): slot (row, cp) receives global chunk cp^(row&7).
template <int MODE>
__global__ __launch_bounds__(256) void k_gemm(
    const ushortT* __restrict__ A, const ushortT* __restrict__ Bt,
    const float* __restrict__ U, void* __restrict__ FoutV,
    const ushortT* __restrict__ Xbf, ushortT* __restrict__ G, int s,
    const float* __restrict__ xstar, float* __restrict__ jac) {
    __shared__ __align__(16) ushortT lA[2][64 * BK];
    __shared__ __align__(16) ushortT lB[2][64 * BK];
    const int tid = threadIdx.x;
    const int wg = blockIdx.x;
    const int chunk = wg & 7, pos = wg >> 3;
    const int bm = (chunk >> 1) * 8 + (pos >> 4);
    const int bn = (chunk & 1) * 16 + (pos & 15);

    f32x4 acc[2][2] = {};

    const int w = tid >> 6, lane = tid & 63;
    const int wr = w >> 1, wc = w & 1;           // wave grid 2x2; wave tile 32x32
    const int lr = lane & 15, hi = lane >> 4;

#define STAGE(buf, kt) do {                                                               \
        _Pragma("unroll")                                                                 \
        for (int i = 0; i < 2; ++i) {                                                     \
            const int idx = i * 256 + tid;                                                \
            const int row = idx >> 3, c = (idx & 7) ^ (row & 7);                          \
            gload_lds16(A + (size_t)(bm * 64 + row) * NDIM + (kt) * BK + c * 8,           \
                        &lA[buf][idx * 8]);                                               \
        }                                                                                 \
        _Pragma("unroll")                                                                 \
        for (int i = 0; i < 2; ++i) {                                                     \
            const int idx = i * 256 + tid;                                                \
            const int row = idx >> 3, c = (idx & 7) ^ (row & 7);                          \
            gload_lds16(Bt + (size_t)(bn * 64 + row) * NDIM + (kt) * BK + c * 8,          \
                        &lB[buf][idx * 8]);                                               \
        }                                                                                 \
    } while (0)

    STAGE(0, 0);
    int cur = 0;
    for (int kt = 0; kt < NDIM / BK; ++kt) {
        __syncthreads();
        if (kt + 1 < NDIM / BK) STAGE(cur ^ 1, kt + 1);
#pragma unroll
        for (int h = 0; h < 2; ++h) {
            bf16x8 af[2], bfr[2];
#pragma unroll
            for (int m = 0; m < 2; ++m) {
                const int r = wr * 32 + m * 16 + lr;
                af[m] = *(const bf16x8*)&lA[cur][r * BK + (((h * 4 + hi) ^ (r & 7)) * 8)];
            }
#pragma unroll
            for (int n = 0; n < 2; ++n) {
                const int rb = wc * 32 + n * 16 + lr;
                bfr[n] = *(const bf16x8*)&lB[cur][rb * BK + (((h * 4 + hi) ^ (rb & 7)) * 8)];
            }
#pragma unroll
            for (int m = 0; m < 2; ++m)
#pragma unroll
                for (int n = 0; n < 2; ++n)
                    acc[m][n] = __builtin_amdgcn_mfma_f32_16x16x32_bf16(af[m], bfr[n], acc[m][n], 0, 0, 0);
        }
        cur ^= 1;
    }
#undef STAGE

    const int r0 = hi * 4;   // C/D: col = lane&15, row = hi*4 + reg
    if (MODE == 0) {
        float* Fout = (float*)FoutV;
#pragma unroll
        for (int m = 0; m < 2; ++m) {
            const int row = bm * 64 + wr * 32 + m * 16 + r0;
#pragma unroll
            for (int n = 0; n < 2; ++n) {
                const int col = bn * 64 + wc * 32 + n * 16 + lr;
#pragma unroll
                for (int r = 0; r < 4; ++r) {
                    const size_t o = (size_t)(row + r) * NDIM + col;
                    Fout[o] = tanh_fast(acc[m][n][r] + U[o]);
                }
            }
        }
    } else if (MODE == 2) {
        ushortT* Fout = (ushortT*)FoutV;
#pragma unroll
        for (int m = 0; m < 2; ++m) {
            const int row = bm * 64 + wr * 32 + m * 16 + r0;
#pragma unroll
            for (int n = 0; n < 2; ++n) {
                const int col = bn * 64 + wc * 32 + n * 16 + lr;
#pragma unroll
                for (int r = 0; r < 4; ++r) {
                    const size_t o = (size_t)(row + r) * NDIM + col;
                    const float f = tanh_fast(acc[m][n][r] + U[o]);
                    Fout[o] = f2bf(f);
                    G[(size_t)s * NTOT + o] = f2bf(f - bf2f(Xbf[o]));
                }
            }
        }
    } else {  // MODE 1: Hutchinson accumulate
        float psum = 0.f;
#pragma unroll
        for (int m = 0; m < 2; ++m) {
            const int row = bm * 64 + wr * 32 + m * 16 + r0;
#pragma unroll
            for (int n = 0; n < 2; ++n) {
                const int col = bn * 64 + wc * 32 + n * 16 + lr;
#pragma unroll
                for (int r = 0; r < 4; ++r) {
                    const size_t o = (size_t)(row + r) * NDIM + col;
                    const float t = xstar[o];
                    const float tang = (1.f - t * t) * acc[m][n][r];
                    psum += tang * tang;
                }
            }
        }
#pragma unroll
        for (int off = 32; off > 0; off >>= 1) psum += __shfl_down(psum, off);
        __syncthreads();
        float* red = (float*)lA;
        if (lane == 0) red[w] = psum;
        __syncthreads();
        if (tid == 0)
            atomicAdd(jac, (red[0] + red[1] + red[2] + red[3]) * (1.0f / (float)NTOT));
    }
}

// ---------------- dots: row/col S of gram over bf16 residuals, compile-time CNT/S.
// All CNT slot-loads issue as one batch (16B each); self-dot reuses v[S] registers.
template <int CNT, int S>
__global__ __launch_bounds__(256) void k_dotsG(const ushortT* __restrict__ G,
                                               float* __restrict__ dots) {
    const int i = blockIdx.x * blockDim.x + threadIdx.x;   // grid sized exactly N16
    uint4 v[CNT];
#pragma unroll
    for (int j = 0; j < CNT; ++j)
        v[j] = ((const uint4*)G)[(size_t)j * N16 + i];
    float gs[8];
    unpack8(v[S], gs);
    float d[CNT];
#pragma unroll
    for (int j = 0; j < CNT; ++j) {
        float gj[8];
        unpack8(v[j], gj);
        float t = 0.f;
#pragma unroll
        for (int e = 0; e < 8; ++e) t += gs[e] * gj[e];
        d[j] = t;
    }
    const int w = threadIdx.x >> 6, lane = threadIdx.x & 63;
    __shared__ float red[4][CNT];
#pragma unroll
    for (int j = 0; j < CNT; ++j) {
        float t = d[j];
#pragma unroll
        for (int off = 32; off > 0; off >>= 1) t += __shfl_down(t, off);
        if (lane == 0) red[w][j] = t;
    }
    __syncthreads();
    if (threadIdx.x < CNT) {
        const int j = threadIdx.x;
        const float t = red[0][j] + red[1][j] + red[2][j] + red[3][j];
        atomicAdd(&dots[S * 5 + j], t);
        if (j != S) atomicAdd(&dots[j * 5 + S], t);
    }
}

// ---------------- mix: per-block alpha solve; Abf = bf16(sum a_j F_j); compile-time NK.
//                  finisher zeroes dots row/col s for the next accumulation
template <int NK>
__global__ __launch_bounds__(256) void k_mix(const ushortT* __restrict__ F,
                                             float* __restrict__ dots,
                                             ushortT* __restrict__ Abf, int s) {
    __shared__ float sa[5];
    if (threadIdx.x == 0) solve5(dots, sa, NK);
    __syncthreads();
    float a[NK];
#pragma unroll
    for (int j = 0; j < NK; ++j) a[j] = sa[j];

    const int i = blockIdx.x * blockDim.x + threadIdx.x;   // grid sized exactly N16
    uint4 v[NK];
#pragma unroll
    for (int j = 0; j < NK; ++j)
        v[j] = ((const uint4*)F)[(size_t)j * N16 + i];
    float sv[8] = {0.f, 0.f, 0.f, 0.f, 0.f, 0.f, 0.f, 0.f};
#pragma unroll
    for (int j = 0; j < NK; ++j) {
        float fj[8];
        unpack8(v[j], fj);
#pragma unroll
        for (int e = 0; e < 8; ++e) sv[e] += a[j] * fj[e];
    }
    ((uint4*)Abf)[i] = pack8(sv);
    // finisher: all blocks have read dots (solve5 prologue) before the counter saturates
    if (threadIdx.x == 0) {
        int* counter = (int*)(dots + 31);
        const int old = atomicAdd(counter, 1);
        if (old == (int)gridDim.x - 1) {
#pragma unroll
            for (int j = 0; j < 5; ++j) { dots[s * 5 + j] = 0.f; dots[j * 5 + s] = 0.f; }
            atomicExch(counter, 0);
        }
    }
}

// ---------------- eps: Rademacher +/-1 in bf16
__global__ void k_eps(ushortT* __restrict__ E) {
    const int stride = gridDim.x * blockDim.x;
    for (int i = blockIdx.x * blockDim.x + threadIdx.x; i < N4; i += stride) {
        ushort4 p;
        p.x = (hash_u32(4u * i + 0u) & 1u) ? 0xBF80u : 0x3F80u;
        p.y = (hash_u32(4u * i + 1u) & 1u) ? 0xBF80u : 0x3F80u;
        p.z = (hash_u32(4u * i + 2u) & 1u) ? 0xBF80u : 0x3F80u;
        p.w = (hash_u32(4u * i + 3u) & 1u) ? 0xBF80u : 0x3F80u;
        ((ushort4*)E)[i] = p;
    }
}

static inline void launch_dots(int cnt, int s, const ushortT* Gs, float* dots,
                               hipStream_t stream) {
    const dim3 g(2048), b(256);
    if (cnt == 2)      k_dotsG<2, 1><<<g, b, 0, stream>>>(Gs, dots);
    else if (cnt == 3) k_dotsG<3, 2><<<g, b, 0, stream>>>(Gs, dots);
    else if (cnt == 4) k_dotsG<4, 3><<<g, b, 0, stream>>>(Gs, dots);
    else switch (s) {
        case 0: k_dotsG<5, 0><<<g, b, 0, stream>>>(Gs, dots); break;
        case 1: k_dotsG<5, 1><<<g, b, 0, stream>>>(Gs, dots); break;
        case 2: k_dotsG<5, 2><<<g, b, 0, stream>>>(Gs, dots); break;
        case 3: k_dotsG<5, 3><<<g, b, 0, stream>>>(Gs, dots); break;
        default: k_dotsG<5, 4><<<g, b, 0, stream>>>(Gs, dots); break;
    }
}
static inline void launch_mix(int nk, const ushortT* Fs, float* dots, ushortT* Abf,
                              int s, hipStream_t stream) {
    const dim3 g(2048), b(256);
    if (nk == 2)      k_mix<2><<<g, b, 0, stream>>>(Fs, dots, Abf, s);
    else if (nk == 3) k_mix<3><<<g, b, 0, stream>>>(Fs, dots, Abf, s);
    else if (nk == 4) k_mix<4><<<g, b, 0, stream>>>(Fs, dots, Abf, s);
    else              k_mix<5><<<g, b, 0, stream>>>(Fs, dots, Abf, s);
}

extern "C" void kernel_launch(void* const* d_in, const int* in_sizes, int n_in,
                              void* d_out, int out_size, void* d_ws, size_t ws_size,
                              hipStream_t stream) {
    const float* W = (const float*)d_in[1];   // d_in[0] = x unused (x0 = zeros)
    const float* U = (const float*)d_in[2];
    float* out = (float*)d_out;

    // ws: WT bf16 8MB | Abf bf16 8MB (reused as eps) | F[5] bf16 40MB | G[5] bf16 40MB | dots 32f
    ushortT* WT  = (ushortT*)d_ws;
    ushortT* Abf = WT + (size_t)NTOT;
    ushortT* Fs  = Abf + (size_t)NTOT;
    ushortT* Gs  = Fs + (size_t)5 * NTOT;
    float* dots  = (float*)(Gs + (size_t)5 * NTOT);

    hipMemsetAsync(dots, 0, 32 * sizeof(float), stream);    // dots + finisher counter
    hipMemsetAsync(out + NTOT, 0, sizeof(float), stream);   // jac accumulator

    k_transpose<<<dim3(64, 64), dim3(32, 8), 0, stream>>>(W, WT);
    k_init<<<1024, 256, 0, stream>>>(U, Fs, Gs, Abf, dots);
    // k=1: F1 = tanh(F0 @ W + u); G1 = bf16(F1 - xk) with xk = F0 (= Abf); dots row/col 1
    k_gemm<2><<<GEMM_BLOCKS, 256, 0, stream>>>(Abf, WT, U, Fs + (size_t)1 * NTOT,
                                               Abf, Gs, 1, nullptr, nullptr);
    launch_dots(2, 1, Gs, dots, stream);
    for (int k = 2; k < 19; ++k) {
        const int s = k % 5;
        const int nk = k < 5 ? k : 5;
        const int cnt = (k + 1 < 5) ? (k + 1) : 5;
        launch_mix(nk, Fs, dots, Abf, s, stream);
        k_gemm<2><<<GEMM_BLOCKS, 256, 0, stream>>>(Abf, WT, U, Fs + (size_t)s * NTOT,
                                                   Abf, Gs, s, nullptr, nullptr);
        launch_dots(cnt, s, Gs, dots, stream);
    }
    // k = 19: final iterate straight to d_out in f32 (no dots / no F slot needed)
    launch_mix(5, Fs, dots, Abf, 4, stream);
    k_gemm<0><<<GEMM_BLOCKS, 256, 0, stream>>>(Abf, WT, U, out, nullptr, nullptr, 0,
                                               nullptr, nullptr);
    // jac_reg: independent Rademacher Hutchinson probe
    k_eps<<<1024, 256, 0, stream>>>(Abf);
    k_gemm<1><<<GEMM_BLOCKS, 256, 0, stream>>>(Abf, WT, nullptr, nullptr, nullptr, nullptr, 0,
                                               out, out + NTOT);
}

// Round 9
// 1272.141 us; speedup vs baseline: 1.8113x; 1.8113x over previous
//
#include <hip/hip_runtime.h>

typedef unsigned short ushortT;
typedef short bf16x8 __attribute__((ext_vector_type(8)));   // 8 bf16 in 4 VGPRs
typedef float f32x4 __attribute__((ext_vector_type(4)));

#define NDIM 2048
#define NTOT (2048 * 2048)
#define N4 (NTOT / 4)
#define N16 (NTOT / 8)     // threads at 8 bf16 (16B) per thread
#define BK 64
#define GEMM_BLOCKS 1024   // 64x64 tiles on 32x32 grid, XCD-supertiled
#define PART_N 2048        // partial-reduction width (dotsG/mix grid)

__device__ __forceinline__ ushortT f2bf(float f) {
    unsigned u = __float_as_uint(f);
    u += 0x7fffu + ((u >> 16) & 1u);   // RNE; inputs finite
    return (ushortT)(u >> 16);
}
__device__ __forceinline__ float bf2f(ushortT u) {
    return __uint_as_float((unsigned)u << 16);
}
__device__ __forceinline__ float tanh_fast(float x) {
    float e = __expf(2.0f * x);
    return 1.0f - 2.0f / (e + 1.0f);
}
__device__ __forceinline__ void gload_lds16(const void* g, void* l) {
    __builtin_amdgcn_global_load_lds(
        (const __attribute__((address_space(1))) void*)g,
        (__attribute__((address_space(3))) void*)l, 16, 0, 0);
}
__device__ __forceinline__ unsigned hash_u32(unsigned x) {
    x ^= x >> 16; x *= 0x7feb352du; x ^= x >> 15; x *= 0x846ca68bu; x ^= x >> 16;
    return x;
}
// unpack 8 bf16 (uint4) -> 8 f32
__device__ __forceinline__ void unpack8(uint4 v, float* f) {
    f[0] = __uint_as_float(v.x << 16); f[1] = __uint_as_float(v.x & 0xffff0000u);
    f[2] = __uint_as_float(v.y << 16); f[3] = __uint_as_float(v.y & 0xffff0000u);
    f[4] = __uint_as_float(v.z << 16); f[5] = __uint_as_float(v.z & 0xffff0000u);
    f[6] = __uint_as_float(v.w << 16); f[7] = __uint_as_float(v.w & 0xffff0000u);
}
__device__ __forceinline__ uint4 pack8(const float* f) {
    uint4 v;
    v.x = (unsigned)f2bf(f[0]) | ((unsigned)f2bf(f[1]) << 16);
    v.y = (unsigned)f2bf(f[2]) | ((unsigned)f2bf(f[3]) << 16);
    v.z = (unsigned)f2bf(f[4]) | ((unsigned)f2bf(f[5]) << 16);
    v.w = (unsigned)f2bf(f[6]) | ((unsigned)f2bf(f[7]) << 16);
    return v;
}

// 5x5 ridge-normal-equation solve (LU w/ pivoting, fp64), alpha normalized.
__device__ void solve5(const float* dots, float* alphaOut, int nk) {
    double H[5][5], rhs[5], x[5];
    for (int i = 0; i < nk; ++i) {
        for (int j = 0; j < nk; ++j)
            H[i][j] = (double)dots[i * 5 + j] + (i == j ? 1e-4 : 0.0);
        rhs[i] = 1.0;
    }
    for (int c = 0; c < nk; ++c) {
        int p = c; double mx = fabs(H[c][c]);
        for (int r = c + 1; r < nk; ++r) { double a = fabs(H[r][c]); if (a > mx) { mx = a; p = r; } }
        if (p != c) {
            for (int j = 0; j < nk; ++j) { double tv = H[c][j]; H[c][j] = H[p][j]; H[p][j] = tv; }
            double tr = rhs[c]; rhs[c] = rhs[p]; rhs[p] = tr;
        }
        double d = H[c][c]; if (fabs(d) < 1e-300) d = 1e-300;
        for (int r = c + 1; r < nk; ++r) {
            double f = H[r][c] / d;
            for (int j = c; j < nk; ++j) H[r][j] -= f * H[c][j];
            rhs[r] -= f * rhs[c];
        }
    }
    for (int c = nk - 1; c >= 0; --c) {
        double v = rhs[c];
        for (int j = c + 1; j < nk; ++j) v -= H[c][j] * x[j];
        double d = H[c][c]; if (fabs(d) < 1e-300) d = 1e-300;
        x[c] = v / d;
    }
    double sum = 0.0;
    for (int i = 0; i < nk; ++i) sum += x[i];
    if (sum == 0.0) sum = 1.0;
    for (int i = 0; i < 5; ++i) alphaOut[i] = (i < nk) ? (float)(x[i] / sum) : 0.f;
}

// block-reduce a single float across 4 waves; result valid on tid 0 (via shared)
__device__ __forceinline__ float block_sum(float v, float* s4) {
    const int w = threadIdx.x >> 6, lane = threadIdx.x & 63;
#pragma unroll
    for (int off = 32; off > 0; off >>= 1) v += __shfl_down(v, off);
    if (lane == 0) s4[w] = v;
    __syncthreads();
    return s4[0] + s4[1] + s4[2] + s4[3];
}

// ---------------- transpose + cast: W (f32 [k][n]) -> WT bf16 [n][k]
__global__ void k_transpose(const float* __restrict__ W, ushortT* __restrict__ WT) {
    __shared__ float tile[32][33];
    const int bx = blockIdx.x * 32, by = blockIdx.y * 32;
    const int tx = threadIdx.x, ty = threadIdx.y;  // (32,8)
#pragma unroll
    for (int r = 0; r < 32; r += 8)
        tile[ty + r][tx] = W[(size_t)(by + ty + r) * NDIM + bx + tx];
    __syncthreads();
#pragma unroll
    for (int r = 0; r < 32; r += 8)
        WT[(size_t)(bx + ty + r) * NDIM + by + tx] = f2bf(tile[tx][ty + r]);
}

// ---------------- init: F0(bf16) = G0(bf16) = Abf = bf16(tanh(u));
//                  per-block partial of <g0,g0> -> initPart[bid]  (NO atomics)
__global__ void k_init(const float* __restrict__ U, ushortT* __restrict__ F0,
                       ushortT* __restrict__ G0, ushortT* __restrict__ Abf,
                       float* __restrict__ initPart) {
    const int stride = gridDim.x * blockDim.x;
    float psum = 0.f;
    for (int i = blockIdx.x * blockDim.x + threadIdx.x; i < N4; i += stride) {
        float4 u = ((const float4*)U)[i];
        float4 t;
        t.x = tanh_fast(u.x); t.y = tanh_fast(u.y);
        t.z = tanh_fast(u.z); t.w = tanh_fast(u.w);
        ushort4 p; p.x = f2bf(t.x); p.y = f2bf(t.y); p.z = f2bf(t.z); p.w = f2bf(t.w);
        ((ushort4*)F0)[i] = p;
        ((ushort4*)G0)[i] = p;
        ((ushort4*)Abf)[i] = p;
        float a = bf2f(p.x), b = bf2f(p.y), c = bf2f(p.z), d = bf2f(p.w);
        psum += a * a + b * b + c * c + d * d;
    }
    __shared__ float s4[4];
    const float t = block_sum(psum, s4);
    if (threadIdx.x == 0) initPart[blockIdx.x] = t;
}

// ---------------- GEMM: C = A(bf16)[64 rows] @ Bt(bf16)[64 rows]^T, BK=64, swizzled LDS
// MODE 0: (float*)FoutV = tanh(C + U)                      [f32 final output]
// MODE 1: jacPart[bid] = block partial of sum(((1-xstar^2)*C)^2)   (A = eps)
// MODE 2: f = tanh(C+U); (ushort*)FoutV = bf16(f); G[s] = bf16(f - bf2f(Xbf))
// Grid: 1D, XCD-supertiled (chunk=id&7 owns 8x16 contiguous supertile).
// LDS swizzle (both-sides, rule #21): slot (row, cp) receives global chunk cp^(row&7).
template <int MODE>
__global__ __launch_bounds__(256) void k_gemm(
    const ushortT* __restrict__ A, const ushortT* __restrict__ Bt,
    const float* __restrict__ U, void* __restrict__ FoutV,
    const ushortT* __restrict__ Xbf, ushortT* __restrict__ G, int s,
    const float* __restrict__ xstar, float* __restrict__ jacPart) {
    __shared__ __align__(16) ushortT lA[2][64 * BK];
    __shared__ __align__(16) ushortT lB[2][64 * BK];
    const int tid = threadIdx.x;
    const int wg = blockIdx.x;
    const int chunk = wg & 7, pos = wg >> 3;
    const int bm = (chunk >> 1) * 8 + (pos >> 4);
    const int bn = (chunk & 1) * 16 + (pos & 15);

    f32x4 acc[2][2] = {};

    const int w = tid >> 6, lane = tid & 63;
    const int wr = w >> 1, wc = w & 1;           // wave grid 2x2; wave tile 32x32
    const int lr = lane & 15, hi = lane >> 4;

#define STAGE(buf, kt) do {                                                               \
        _Pragma("unroll")                                                                 \
        for (int i = 0; i < 2; ++i) {                                                     \
            const int idx = i * 256 + tid;                                                \
            const int row = idx >> 3, c = (idx & 7) ^ (row & 7);                          \
            gload_lds16(A + (size_t)(bm * 64 + row) * NDIM + (kt) * BK + c * 8,           \
                        &lA[buf][idx * 8]);                                               \
        }                                                                                 \
        _Pragma("unroll")                                                                 \
        for (int i = 0; i < 2; ++i) {                                                     \
            const int idx = i * 256 + tid;                                                \
            const int row = idx >> 3, c = (idx & 7) ^ (row & 7);                          \
            gload_lds16(Bt + (size_t)(bn * 64 + row) * NDIM + (kt) * BK + c * 8,          \
                        &lB[buf][idx * 8]);                                               \
        }                                                                                 \
    } while (0)

    STAGE(0, 0);
    int cur = 0;
    for (int kt = 0; kt < NDIM / BK; ++kt) {
        __syncthreads();
        if (kt + 1 < NDIM / BK) STAGE(cur ^ 1, kt + 1);
#pragma unroll
        for (int h = 0; h < 2; ++h) {
            bf16x8 af[2], bfr[2];
#pragma unroll
            for (int m = 0; m < 2; ++m) {
                const int r = wr * 32 + m * 16 + lr;
                af[m] = *(const bf16x8*)&lA[cur][r * BK + (((h * 4 + hi) ^ (r & 7)) * 8)];
            }
#pragma unroll
            for (int n = 0; n < 2; ++n) {
                const int rb = wc * 32 + n * 16 + lr;
                bfr[n] = *(const bf16x8*)&lB[cur][rb * BK + (((h * 4 + hi) ^ (rb & 7)) * 8)];
            }
#pragma unroll
            for (int m = 0; m < 2; ++m)
#pragma unroll
                for (int n = 0; n < 2; ++n)
                    acc[m][n] = __builtin_amdgcn_mfma_f32_16x16x32_bf16(af[m], bfr[n], acc[m][n], 0, 0, 0);
        }
        cur ^= 1;
    }
#undef STAGE

    const int r0 = hi * 4;   // C/D: col = lane&15, row = hi*4 + reg
    if (MODE == 0) {
        float* Fout = (float*)FoutV;
#pragma unroll
        for (int m = 0; m < 2; ++m) {
            const int row = bm * 64 + wr * 32 + m * 16 + r0;
#pragma unroll
            for (int n = 0; n < 2; ++n) {
                const int col = bn * 64 + wc * 32 + n * 16 + lr;
#pragma unroll
                for (int r = 0; r < 4; ++r) {
                    const size_t o = (size_t)(row + r) * NDIM + col;
                    Fout[o] = tanh_fast(acc[m][n][r] + U[o]);
                }
            }
        }
    } else if (MODE == 2) {
        ushortT* Fout = (ushortT*)FoutV;
#pragma unroll
        for (int m = 0; m < 2; ++m) {
            const int row = bm * 64 + wr * 32 + m * 16 + r0;
#pragma unroll
            for (int n = 0; n < 2; ++n) {
                const int col = bn * 64 + wc * 32 + n * 16 + lr;
#pragma unroll
                for (int r = 0; r < 4; ++r) {
                    const size_t o = (size_t)(row + r) * NDIM + col;
                    const float f = tanh_fast(acc[m][n][r] + U[o]);
                    Fout[o] = f2bf(f);
                    G[(size_t)s * NTOT + o] = f2bf(f - bf2f(Xbf[o]));
                }
            }
        }
    } else {  // MODE 1: Hutchinson partial (no atomics)
        float psum = 0.f;
#pragma unroll
        for (int m = 0; m < 2; ++m) {
            const int row = bm * 64 + wr * 32 + m * 16 + r0;
#pragma unroll
            for (int n = 0; n < 2; ++n) {
                const int col = bn * 64 + wc * 32 + n * 16 + lr;
#pragma unroll
                for (int r = 0; r < 4; ++r) {
                    const size_t o = (size_t)(row + r) * NDIM + col;
                    const float t = xstar[o];
                    const float tang = (1.f - t * t) * acc[m][n][r];
                    psum += tang * tang;
                }
            }
        }
        __syncthreads();
        __shared__ float s4[4];
        const float t = block_sum(psum, s4);
        if (tid == 0) jacPart[wg] = t;
    }
}

// ---------------- dots partials: row S of gram vs slots j < CNT -> part[j][bid]
template <int CNT, int S>
__global__ __launch_bounds__(256) void k_dotsG(const ushortT* __restrict__ G,
                                               float* __restrict__ part) {
    const int i = blockIdx.x * blockDim.x + threadIdx.x;   // grid exactly N16
    uint4 v[CNT];
#pragma unroll
    for (int j = 0; j < CNT; ++j)
        v[j] = ((const uint4*)G)[(size_t)j * N16 + i];
    float gs[8];
    unpack8(v[S], gs);
    float d[CNT];
#pragma unroll
    for (int j = 0; j < CNT; ++j) {
        float gj[8];
        unpack8(v[j], gj);
        float t = 0.f;
#pragma unroll
        for (int e = 0; e < 8; ++e) t += gs[e] * gj[e];
        d[j] = t;
    }
    const int w = threadIdx.x >> 6, lane = threadIdx.x & 63;
    __shared__ float red[4][CNT];
#pragma unroll
    for (int j = 0; j < CNT; ++j) {
        float t = d[j];
#pragma unroll
        for (int off = 32; off > 0; off >>= 1) t += __shfl_down(t, off);
        if (lane == 0) red[w][j] = t;
    }
    __syncthreads();
    if (threadIdx.x < CNT)
        part[(size_t)threadIdx.x * PART_N + blockIdx.x] =
            red[0][threadIdx.x] + red[1][threadIdx.x] + red[2][threadIdx.x] + red[3][threadIdx.x];
}

// ---------------- reduce: sum partials -> dots row/col S (WRITE, no zeroing needed);
//                  optional initPart -> dots[0][0]; then solve5 once -> alpha
template <int NK, int S>
__global__ void k_reduce(const float* __restrict__ part,
                         const float* __restrict__ initPart,
                         float* __restrict__ dots, float* __restrict__ alpha) {
    __shared__ float s4[4];
    const int tid = threadIdx.x;   // 256
#pragma unroll
    for (int j = 0; j < NK; ++j) {
        float v = 0.f;
        for (int i = tid; i < PART_N; i += 256) v += part[(size_t)j * PART_N + i];
        const float t = block_sum(v, s4);
        if (tid == 0) {
            dots[S * 5 + j] = t;
            if (j != S) dots[j * 5 + S] = t;
        }
        __syncthreads();
    }
    if (initPart) {
        float v = 0.f;
        for (int i = tid; i < PART_N; i += 256) v += initPart[i];
        const float t = block_sum(v, s4);
        if (tid == 0) dots[0] = t;
        __syncthreads();
    }
    if (tid == 0) {   // __syncthreads above makes this block's global writes visible
        float a[5];
        solve5(dots, a, NK);
#pragma unroll
        for (int i = 0; i < 5; ++i) alpha[i] = a[i];
    }
}

// ---------------- mix: Abf = bf16(sum alpha_j F_j); pure streaming, no atomics
template <int NK>
__global__ __launch_bounds__(256) void k_mix(const ushortT* __restrict__ F,
                                             const float* __restrict__ alpha,
                                             ushortT* __restrict__ Abf) {
    float a[NK];
#pragma unroll
    for (int j = 0; j < NK; ++j) a[j] = alpha[j];
    const int i = blockIdx.x * blockDim.x + threadIdx.x;   // grid exactly N16
    uint4 v[NK];
#pragma unroll
    for (int j = 0; j < NK; ++j)
        v[j] = ((const uint4*)F)[(size_t)j * N16 + i];
    float sv[8] = {0.f, 0.f, 0.f, 0.f, 0.f, 0.f, 0.f, 0.f};
#pragma unroll
    for (int j = 0; j < NK; ++j) {
        float fj[8];
        unpack8(v[j], fj);
#pragma unroll
        for (int e = 0; e < 8; ++e) sv[e] += a[j] * fj[e];
    }
    ((uint4*)Abf)[i] = pack8(sv);
}

// ---------------- eps: Rademacher +/-1 in bf16
__global__ void k_eps(ushortT* __restrict__ E) {
    const int stride = gridDim.x * blockDim.x;
    for (int i = blockIdx.x * blockDim.x + threadIdx.x; i < N4; i += stride) {
        ushort4 p;
        p.x = (hash_u32(4u * i + 0u) & 1u) ? 0xBF80u : 0x3F80u;
        p.y = (hash_u32(4u * i + 1u) & 1u) ? 0xBF80u : 0x3F80u;
        p.z = (hash_u32(4u * i + 2u) & 1u) ? 0xBF80u : 0x3F80u;
        p.w = (hash_u32(4u * i + 3u) & 1u) ? 0xBF80u : 0x3F80u;
        ((ushort4*)E)[i] = p;
    }
}

// ---------------- jac final reduce: out[NTOT] = sum(jacPart)/NTOT
__global__ void k_jacred(const float* __restrict__ jacPart, float* __restrict__ jac) {
    __shared__ float s4[4];
    float v = 0.f;
    for (int i = threadIdx.x; i < GEMM_BLOCKS; i += 256) v += jacPart[i];
    const float t = block_sum(v, s4);
    if (threadIdx.x == 0) *jac = t * (1.0f / (float)NTOT);
}

static inline void launch_dots(int cnt, int s, const ushortT* Gs, float* part,
                               hipStream_t stream) {
    const dim3 g(PART_N), b(256);
    if (cnt == 2)      k_dotsG<2, 1><<<g, b, 0, stream>>>(Gs, part);
    else if (cnt == 3) k_dotsG<3, 2><<<g, b, 0, stream>>>(Gs, part);
    else if (cnt == 4) k_dotsG<4, 3><<<g, b, 0, stream>>>(Gs, part);
    else switch (s) {
        case 0: k_dotsG<5, 0><<<g, b, 0, stream>>>(Gs, part); break;
        case 1: k_dotsG<5, 1><<<g, b, 0, stream>>>(Gs, part); break;
        case 2: k_dotsG<5, 2><<<g, b, 0, stream>>>(Gs, part); break;
        case 3: k_dotsG<5, 3><<<g, b, 0, stream>>>(Gs, part); break;
        default: k_dotsG<5, 4><<<g, b, 0, stream>>>(Gs, part); break;
    }
}
static inline void launch_reduce(int nk, int sprev, const float* part, const float* initPart,
                                 float* dots, float* alpha, hipStream_t stream) {
    const dim3 g(1), b(256);
    if (nk == 2)      k_reduce<2, 1><<<g, b, 0, stream>>>(part, initPart, dots, alpha);
    else if (nk == 3) k_reduce<3, 2><<<g, b, 0, stream>>>(part, initPart, dots, alpha);
    else if (nk == 4) k_reduce<4, 3><<<g, b, 0, stream>>>(part, initPart, dots, alpha);
    else switch (sprev) {
        case 0: k_reduce<5, 0><<<g, b, 0, stream>>>(part, initPart, dots, alpha); break;
        case 1: k_reduce<5, 1><<<g, b, 0, stream>>>(part, initPart, dots, alpha); break;
        case 2: k_reduce<5, 2><<<g, b, 0, stream>>>(part, initPart, dots, alpha); break;
        case 3: k_reduce<5, 3><<<g, b, 0, stream>>>(part, initPart, dots, alpha); break;
        default: k_reduce<5, 4><<<g, b, 0, stream>>>(part, initPart, dots, alpha); break;
    }
}
static inline void launch_mix(int nk, const ushortT* Fs, const float* alpha, ushortT* Abf,
                              hipStream_t stream) {
    const dim3 g(PART_N), b(256);
    if (nk == 2)      k_mix<2><<<g, b, 0, stream>>>(Fs, alpha, Abf);
    else if (nk == 3) k_mix<3><<<g, b, 0, stream>>>(Fs, alpha, Abf);
    else if (nk == 4) k_mix<4><<<g, b, 0, stream>>>(Fs, alpha, Abf);
    else              k_mix<5><<<g, b, 0, stream>>>(Fs, alpha, Abf);
}

extern "C" void kernel_launch(void* const* d_in, const int* in_sizes, int n_in,
                              void* d_out, int out_size, void* d_ws, size_t ws_size,
                              hipStream_t stream) {
    const float* W = (const float*)d_in[1];   // d_in[0] = x unused (x0 = zeros)
    const float* U = (const float*)d_in[2];
    float* out = (float*)d_out;

    // ws: WT 8MB | Abf 8MB | F[5] 40MB | G[5] 40MB | dots 32f | alpha 8f | part 5*2048 | initPart 2048 | jacPart 1024
    ushortT* WT   = (ushortT*)d_ws;
    ushortT* Abf  = WT + (size_t)NTOT;
    ushortT* Fs   = Abf + (size_t)NTOT;
    ushortT* Gs   = Fs + (size_t)5 * NTOT;
    float* dots   = (float*)(Gs + (size_t)5 * NTOT);
    float* alpha  = dots + 32;
    float* part   = alpha + 8;
    float* initPart = part + 5 * PART_N;
    float* jacPart  = initPart + PART_N;

    k_transpose<<<dim3(64, 64), dim3(32, 8), 0, stream>>>(W, WT);
    k_init<<<PART_N, 256, 0, stream>>>(U, Fs, Gs, Abf, initPart);
    // k=1: F1 = tanh(F0 @ W + u); G1 = bf16(F1 - xk) with xk = F0 (= Abf)
    k_gemm<2><<<GEMM_BLOCKS, 256, 0, stream>>>(Abf, WT, U, Fs + (size_t)1 * NTOT,
                                               Abf, Gs, 1, nullptr, nullptr);
    launch_dots(2, 1, Gs, part, stream);
    for (int k = 2; k < 20; ++k) {
        const int s = k % 5;
        const int sprev = (k - 1) % 5;
        const int nk = k < 5 ? k : 5;
        // reduce partials from previous dotsG (row/col sprev, cnt == nk) + solve -> alpha
        launch_reduce(nk, sprev, part, (k == 2) ? initPart : nullptr, dots, alpha, stream);
        launch_mix(nk, Fs, alpha, Abf, stream);
        if (k < 19) {
            const int cnt = (k + 1 < 5) ? (k + 1) : 5;
            k_gemm<2><<<GEMM_BLOCKS, 256, 0, stream>>>(Abf, WT, U, Fs + (size_t)s * NTOT,
                                                       Abf, Gs, s, nullptr, nullptr);
            launch_dots(cnt, s, Gs, part, stream);
        } else {
            // final iterate straight to d_out in f32
            k_gemm<0><<<GEMM_BLOCKS, 256, 0, stream>>>(Abf, WT, U, out, nullptr, nullptr, 0,
                                                       nullptr, nullptr);
        }
    }
    // jac_reg: independent Rademacher Hutchinson probe
    k_eps<<<1024, 256, 0, stream>>>(Abf);
    k_gemm<1><<<GEMM_BLOCKS, 256, 0, stream>>>(Abf, WT, nullptr, nullptr, nullptr, nullptr, 0,
                                               out, jacPart);
    k_jacred<<<1, 256, 0, stream>>>(jacPart, out + NTOT);
}